// Round 9
// baseline (305.192 us; speedup 1.0000x reference)
//
#include <hip/hip_runtime.h>
#include <hip/hip_bf16.h>
#include <cstdint>
#include <cstddef>

// Problem constants (fixed by reference)
#define BB 32
#define NN 8192
#define DIN 64
#define DOUT 128
#define NR 4
#define BN_EPS 1e-5f
#define CHUNKS 32  // NN / 256

// INSTRUMENTATION ROUND: REP=3 idempotent repeats around the phases to be
// attributed (T-loop in k_compute, gather/store loop in k_out) lift both
// kernels above the 78us workspace-poison fills that have monopolized the
// top-5 counter rows since r3. Attribution: dur = fixed + 3*repeated, with
// r8's 1x sum known -> both components solve. Score this round is
// deliberately sacrificed for the first full PMC rows in 6 rounds.
#define REP 3

typedef float nfloat4 __attribute__((ext_vector_type(4)));
typedef float floatx4 __attribute__((ext_vector_type(4)));
typedef short short8 __attribute__((ext_vector_type(8)));

__device__ inline void pack2(float a, float b, short8& dst, int idx) {
  __hip_bfloat162 h = __float22bfloat162_rn(make_float2(a, b));
  const unsigned int bits = *(unsigned int*)&h;
  dst[idx] = (short)(bits & 0xffffu);
  dst[idx + 1] = (short)(bits >> 16);
}

// LDS 16B-group swizzle (counter-verification of this is a goal this round)
__device__ inline int swz(int n) { return (n ^ (n >> 2) ^ (n >> 5)) & 7; }

// ---------------------------------------------------------------------------
// K1 (MFMA): r8 structure verbatim; T-loop repeated REP x (idempotent max
// refold of identical values; __syncthreads between reps blocks CSE).
__global__ void __launch_bounds__(256) k_compute(
    const float* __restrict__ x, const float* __restrict__ W,
    const int* __restrict__ ring, float* __restrict__ part) {
  const int b = blockIdx.y;
  const int cx = blockIdx.x;
  const int n0 = cx * 256;
  const int wave = (int)threadIdx.x >> 6;
  const int lane = (int)threadIdx.x & 63;
  const int quad = lane >> 4;
  const int l16 = lane & 15;
  const float* xb = x + (size_t)b * DIN * NN;
  const int* rgb = ring + (size_t)b * NN;

  __shared__ short8 lx[256 * 8];  // 32 KB bf16 tile [n][8 dblk], swizzled

  // ---- stage (runs ONCE)
  {
    const float* xr = xb + (size_t)(wave * 16) * NN + n0 + 4 * lane;
#pragma unroll
    for (int grp = 0; grp < 2; ++grp) {
      nfloat4 L[8];
#pragma unroll
      for (int j = 0; j < 8; ++j)
        L[j] = *(const nfloat4*)&xr[(size_t)(grp * 8 + j) * NN];
#pragma unroll
      for (int i = 0; i < 4; ++i) {
        short8 v;
        pack2(L[0][i], L[1][i], v, 0);
        pack2(L[2][i], L[3][i], v, 2);
        pack2(L[4][i], L[5][i], v, 4);
        pack2(L[6][i], L[7][i], v, 6);
        const int ni = 4 * lane + i;
        lx[ni * 8 + ((wave * 2 + grp) ^ swz(ni))] = v;
      }
    }
  }

  // A fragments for all 4 rings
  short8 afr[NR][2][2];
#pragma unroll
  for (int r = 0; r < NR; ++r) {
#pragma unroll
    for (int tt = 0; tt < 2; ++tt) {
      const int chan = (wave + 4 * tt) * 16 + l16;
      const float* wr = W + ((size_t)r * DOUT + chan) * DIN + quad * 8;
#pragma unroll
      for (int ks = 0; ks < 2; ++ks) {
        const float4 w0 = *(const float4*)&wr[ks * 32];
        const float4 w1 = *(const float4*)&wr[ks * 32 + 4];
        short8 a;
        pack2(w0.x, w0.y, a, 0);
        pack2(w0.z, w0.w, a, 2);
        pack2(w1.x, w1.y, a, 4);
        pack2(w1.z, w1.w, a, 6);
        afr[r][tt][ks] = a;
      }
    }
  }

  floatx4 rmax[2][NR];
#pragma unroll
  for (int tt = 0; tt < 2; ++tt)
#pragma unroll
    for (int r = 0; r < NR; ++r)
      rmax[tt][r] = {-INFINITY, -INFINITY, -INFINITY, -INFINITY};

  // ---- T-loop, repeated REP x for attribution
#pragma unroll 1
  for (int rep = 0; rep < REP; ++rep) {
    __syncthreads();  // also covers the original stage->read barrier
#pragma unroll 4
    for (int T = 0; T < 16; ++T) {
      const int n = T * 16 + l16;
      const short8 b0 = lx[n * 8 + (quad ^ swz(n))];
      const short8 b1 = lx[n * 8 + ((4 + quad) ^ swz(n))];
      const int rr = rgb[n0 + n];
#pragma unroll
      for (int r = 0; r < NR; ++r) {
        floatx4 acc0 = {0.f, 0.f, 0.f, 0.f};
        floatx4 acc1 = {0.f, 0.f, 0.f, 0.f};
        acc0 = __builtin_amdgcn_mfma_f32_16x16x32_bf16(afr[r][0][0], b0, acc0, 0, 0, 0);
        acc0 = __builtin_amdgcn_mfma_f32_16x16x32_bf16(afr[r][0][1], b1, acc0, 0, 0, 0);
        acc1 = __builtin_amdgcn_mfma_f32_16x16x32_bf16(afr[r][1][0], b0, acc1, 0, 0, 0);
        acc1 = __builtin_amdgcn_mfma_f32_16x16x32_bf16(afr[r][1][1], b1, acc1, 0, 0, 0);
        if (rr == r) {
#pragma unroll
          for (int p = 0; p < 4; ++p) {
            rmax[0][r][p] = fmaxf(rmax[0][r][p], acc0[p]);
            rmax[1][r][p] = fmaxf(rmax[1][r][p], acc1[p]);
          }
        }
      }
    }
  }

  // epilogue (once): butterfly + one plain store per (ring, chan)
  float* slot = part + (size_t)(b * CHUNKS + cx) * NR * DOUT;
#pragma unroll
  for (int tt = 0; tt < 2; ++tt) {
#pragma unroll
    for (int r = 0; r < NR; ++r) {
#pragma unroll
      for (int p = 0; p < 4; ++p) {
        float v = rmax[tt][r][p];
        v = fmaxf(v, __shfl_xor(v, 1, 64));
        v = fmaxf(v, __shfl_xor(v, 2, 64));
        v = fmaxf(v, __shfl_xor(v, 4, 64));
        v = fmaxf(v, __shfl_xor(v, 8, 64));
        if (l16 == 0) {
          const int chan = (wave + 4 * tt) * 16 + quad * 4 + p;
          slot[r * DOUT + chan] = v;
        }
      }
    }
  }
}

// ---------------------------------------------------------------------------
// K2: r8 structure verbatim; gather/store loop repeated REP x (idempotent
// re-stores of identical values).
__global__ void __launch_bounds__(256) k_out(
    const float* __restrict__ bias, const float* __restrict__ gamma,
    const float* __restrict__ beta, const float* __restrict__ mean,
    const float* __restrict__ var, const int* __restrict__ ring,
    const float* __restrict__ part, float* __restrict__ out) {
  const int b = blockIdx.z;
  const int og = blockIdx.y;
  const int n0 = blockIdx.x * 1024;
  const int t = (int)threadIdx.x;

  __shared__ float lut[32 * NR * 32];  // [oo][r][c32], 16 KB
  {
    const int oo = t >> 3;
    const int r = (t >> 1) & 3;
    const int c0 = (t & 1) * 16;
    const int o = og * 32 + oo;
    const float* ps = part + (size_t)b * CHUNKS * NR * DOUT + r * DOUT + o;
    float raw = -INFINITY;
#pragma unroll
    for (int c = 0; c < CHUNKS; ++c)
      raw = fmaxf(raw, ps[(size_t)c * NR * DOUT]);
    const int tt = r * DOUT + o;
    const float sc = gamma[tt] * rsqrtf(var[tt] + BN_EPS);
    const float val = (raw + bias[tt] - mean[tt]) * sc + beta[tt];
    nfloat4 v4 = {val, val, val, val};
    float* dst = &lut[(oo * NR + r) * 32 + c0];
#pragma unroll
    for (int k = 0; k < 4; ++k) *(nfloat4*)&dst[k * 4] = v4;
  }

  const int n = n0 + t * 4;
  const int4 rg = *(const int4*)&ring[(size_t)b * NN + n];
  const int l31 = t & 31;
  const float* p0 = &lut[rg.x * 32 + l31];
  const float* p1 = &lut[rg.y * 32 + l31];
  const float* p2 = &lut[rg.z * 32 + l31];
  const float* p3 = &lut[rg.w * 32 + l31];
  float* orow = out + ((size_t)b * DOUT + og * 32) * NN + n;

#pragma unroll 1
  for (int rep = 0; rep < REP; ++rep) {
    __syncthreads();  // also covers the original LUT->read barrier
#pragma unroll 8
    for (int oo = 0; oo < 32; ++oo) {
      nfloat4 v;
      v.x = p0[oo * 128];
      v.y = p1[oo * 128];
      v.z = p2[oo * 128];
      v.w = p3[oo * 128];
      *(nfloat4*)(orow + (size_t)oo * NN) = v;
    }
  }
}

// ---------------------------------------------------------------------------
extern "C" void kernel_launch(void* const* d_in, const int* in_sizes, int n_in,
                              void* d_out, int out_size, void* d_ws, size_t ws_size,
                              hipStream_t stream) {
  const float* x = (const float*)d_in[0];
  const int* ring = (const int*)d_in[1];
  const float* W = (const float*)d_in[2];
  const float* bias = (const float*)d_in[3];
  const float* gamma = (const float*)d_in[4];
  const float* beta = (const float*)d_in[5];
  const float* mean = (const float*)d_in[6];
  const float* var = (const float*)d_in[7];
  float* out = (float*)d_out;

  float* part = (float*)d_ws;  // 2 MB, fully overwritten -> no memset

  k_compute<<<dim3(CHUNKS, BB), 256, 0, stream>>>(x, W, ring, part);
  k_out<<<dim3(NN / 1024, DOUT / 32, BB), 256, 0, stream>>>(bias, gamma, beta, mean,
                                                            var, ring, part, out);
}

// Round 10
// 225.912 us; speedup vs baseline: 1.3509x; 1.3509x over previous
//
#include <hip/hip_runtime.h>
#include <hip/hip_bf16.h>
#include <cstdint>
#include <cstddef>

// Problem constants (fixed by reference)
#define BB 32
#define NN 8192
#define DIN 64
#define DOUT 128
#define NR 4
#define BN_EPS 1e-5f
#define CHUNKS 8  // NN / 1024 : one partial slot per (b, 1024-pt block)

typedef float nfloat4 __attribute__((ext_vector_type(4)));
typedef float floatx4 __attribute__((ext_vector_type(4)));
typedef short short8 __attribute__((ext_vector_type(8)));

// Workspace: float part[BB*CHUNKS][NR][DOUT] = 512 KB of per-block partial
// maxima; fully overwritten each launch -> no memset, no atomics.
//
// r9 instrumentation findings driving this version:
//   t (T-loop)  ~15.5us/pass, MFMA floor 2.3us  -> not the problem
//   g (k_out store loop) ~20us for 128MB = 6.4 TB/s -> AT write roofline
//   k1 fixed (stage/prologue) ~60us, invariant across 3 stage styles
//   -> amortize the per-block fixed cost 4x (1024-pt blocks) and overlap
//      staging with compute via a 2x32KB LDS double buffer + split
//      load/pack pipeline (loads for c+1 fly under tloop(c)).

__device__ inline void pack2(float a, float b, short8& dst, int idx) {
  __hip_bfloat162 h = __float22bfloat162_rn(make_float2(a, b));
  const unsigned int bits = *(unsigned int*)&h;
  dst[idx] = (short)(bits & 0xffffu);
  dst[idx + 1] = (short)(bits >> 16);
}

// LDS 16B-group swizzle (counter-verified conflict-free in r9: conflicts=0)
__device__ inline int swz(int n) { return (n ^ (n >> 2) ^ (n >> 5)) & 7; }

// ---------------------------------------------------------------------------
// K1 (MFMA): block = (b, 1024-pt chunk), 8 waves, grid 8x32 = 256 blocks.
// Wave w owns chan-tile w (chan = w*16+l16) and stages d-rows w*8..w*8+7
// (each sub-chunk continues the same rows at +1KB -> 4KB sequential streams).
// Pipeline per sub-chunk c: pack_write(c) -> issue loads(c+1) -> barrier ->
// tloop(c)  [loads for c+1 in flight under the MFMAs].
__global__ void __launch_bounds__(512) k_compute(
    const float* __restrict__ x, const float* __restrict__ W,
    const int* __restrict__ ring, float* __restrict__ part) {
  const int b = blockIdx.y;
  const int big = blockIdx.x;   // 1024-pt chunk index
  const int n0 = big * 1024;
  const int tid = (int)threadIdx.x;
  const int wave = tid >> 6;    // 0..7
  const int lane = tid & 63;
  const int quad = lane >> 4;
  const int l16 = lane & 15;
  const float* xb = x + (size_t)b * DIN * NN;
  const int* rgb = ring + (size_t)b * NN + n0;

  __shared__ short8 lx[2][256 * 8];  // 2 x 32 KB bf16 [n][dblk], swizzled

  // A fragments: afr[r][ks] covers A[m=l16 -> chan=w*16+l16][k=ks*32+quad*8+j]
  short8 afr[NR][2];
#pragma unroll
  for (int r = 0; r < NR; ++r) {
    const int chan = wave * 16 + l16;
    const float* wr = W + ((size_t)r * DOUT + chan) * DIN + quad * 8;
#pragma unroll
    for (int ks = 0; ks < 2; ++ks) {
      const float4 w0 = *(const float4*)&wr[ks * 32];
      const float4 w1 = *(const float4*)&wr[ks * 32 + 4];
      short8 a;
      pack2(w0.x, w0.y, a, 0);
      pack2(w0.z, w0.w, a, 2);
      pack2(w1.x, w1.y, a, 4);
      pack2(w1.z, w1.w, a, 6);
      afr[r][ks] = a;
    }
  }

  floatx4 rmax[NR];
#pragma unroll
  for (int r = 0; r < NR; ++r)
    rmax[r] = {-INFINITY, -INFINITY, -INFINITY, -INFINITY};

  // --- pipeline helpers (named register sets; static indexing only) ---
  // loads: L[j] = row (wave*8+j) of sub-chunk c, 16B per thread per row
  auto LOADL = [&](nfloat4 (&L)[8], int c) {
    const float* base = xb + (size_t)(wave * 8) * NN + n0 + c * 256 + 4 * lane;
#pragma unroll
    for (int j = 0; j < 8; ++j)
      L[j] = *(const nfloat4*)&base[(size_t)j * NN];
  };
  // pack 8x4 in-register transpose -> swizzled ds_write_b128 (dblk = wave)
  auto PACKW = [&](int buf, const nfloat4 (&L)[8]) {
#pragma unroll
    for (int i = 0; i < 4; ++i) {
      short8 v;
      pack2(L[0][i], L[1][i], v, 0);
      pack2(L[2][i], L[3][i], v, 2);
      pack2(L[4][i], L[5][i], v, 4);
      pack2(L[6][i], L[7][i], v, 6);
      const int ni = 4 * lane + i;
      lx[buf][ni * 8 + (wave ^ swz(ni))] = v;
    }
  };
  // T-loop over one staged 256-pt sub-chunk
  auto TLOOP = [&](int buf, int c) {
#pragma unroll 4
    for (int T = 0; T < 16; ++T) {
      const int n = T * 16 + l16;
      const short8 b0 = lx[buf][n * 8 + (quad ^ swz(n))];        // d=quad*8+j
      const short8 b1 = lx[buf][n * 8 + ((4 + quad) ^ swz(n))];  // d=32+...
      const int rr = rgb[c * 256 + n];
#pragma unroll
      for (int r = 0; r < NR; ++r) {
        floatx4 acc = {0.f, 0.f, 0.f, 0.f};
        acc = __builtin_amdgcn_mfma_f32_16x16x32_bf16(afr[r][0], b0, acc, 0, 0, 0);
        acc = __builtin_amdgcn_mfma_f32_16x16x32_bf16(afr[r][1], b1, acc, 0, 0, 0);
        if (rr == r) {  // exec-masked fold; MFMAs above stay convergent
#pragma unroll
          for (int p = 0; p < 4; ++p) rmax[r][p] = fmaxf(rmax[r][p], acc[p]);
        }
      }
    }
  };

  // --- 4 sub-chunks, 2-deep pipeline, one barrier per iteration ---
  nfloat4 LA[8], LB[8];
  LOADL(LA, 0);
  // c=0
  PACKW(0, LA);
  LOADL(LB, 1);        // flies under tloop(0)
  __syncthreads();
  TLOOP(0, 0);
  // c=1
  PACKW(1, LB);
  LOADL(LA, 2);        // flies under tloop(1)
  __syncthreads();
  TLOOP(1, 1);
  // c=2
  PACKW(0, LA);
  LOADL(LB, 3);        // flies under tloop(2)
  __syncthreads();
  TLOOP(0, 2);
  // c=3
  PACKW(1, LB);
  __syncthreads();
  TLOOP(1, 3);

  // epilogue: butterfly over the 16 point-columns; lanes l16==0 store one
  // value per (r, chan) into this block's private slot. Full coverage:
  // 8 waves x 4 quads x 4 p x 4 r = 512 = NR*DOUT.
  float* slot = part + (size_t)(b * CHUNKS + big) * NR * DOUT;
#pragma unroll
  for (int r = 0; r < NR; ++r) {
#pragma unroll
    for (int p = 0; p < 4; ++p) {
      float v = rmax[r][p];
      v = fmaxf(v, __shfl_xor(v, 1, 64));
      v = fmaxf(v, __shfl_xor(v, 2, 64));
      v = fmaxf(v, __shfl_xor(v, 4, 64));
      v = fmaxf(v, __shfl_xor(v, 8, 64));
      if (l16 == 0) {
        const int chan = wave * 16 + quad * 4 + p;
        slot[r * DOUT + chan] = v;
      }
    }
  }
}

// ---------------------------------------------------------------------------
// K2: r8 verbatim (gather/store loop measured AT the 6.4 TB/s write roofline
// in r9); only the LUT reduce now covers CHUNKS=8 per-block partials.
__global__ void __launch_bounds__(256) k_out(
    const float* __restrict__ bias, const float* __restrict__ gamma,
    const float* __restrict__ beta, const float* __restrict__ mean,
    const float* __restrict__ var, const int* __restrict__ ring,
    const float* __restrict__ part, float* __restrict__ out) {
  const int b = blockIdx.z;
  const int og = blockIdx.y;  // 32-channel group
  const int n0 = blockIdx.x * 1024;
  const int t = (int)threadIdx.x;

  __shared__ float lut[32 * NR * 32];  // [oo][r][c32], 16 KB
  {
    const int oo = t >> 3;
    const int r = (t >> 1) & 3;
    const int c0 = (t & 1) * 16;
    const int o = og * 32 + oo;
    const float* ps = part + (size_t)b * CHUNKS * NR * DOUT + r * DOUT + o;
    float raw = -INFINITY;
#pragma unroll
    for (int c = 0; c < CHUNKS; ++c)
      raw = fmaxf(raw, ps[(size_t)c * NR * DOUT]);
    const int tt = r * DOUT + o;
    const float sc = gamma[tt] * rsqrtf(var[tt] + BN_EPS);
    const float val = (raw + bias[tt] - mean[tt]) * sc + beta[tt];
    nfloat4 v4 = {val, val, val, val};
    float* dst = &lut[(oo * NR + r) * 32 + c0];
#pragma unroll
    for (int k = 0; k < 4; ++k) *(nfloat4*)&dst[k * 4] = v4;
  }
  __syncthreads();

  const int n = n0 + t * 4;
  const int4 rg = *(const int4*)&ring[(size_t)b * NN + n];
  const int l31 = t & 31;
  const float* p0 = &lut[rg.x * 32 + l31];
  const float* p1 = &lut[rg.y * 32 + l31];
  const float* p2 = &lut[rg.z * 32 + l31];
  const float* p3 = &lut[rg.w * 32 + l31];
  float* orow = out + ((size_t)b * DOUT + og * 32) * NN + n;

#pragma unroll 8
  for (int oo = 0; oo < 32; ++oo) {
    nfloat4 v;
    v.x = p0[oo * 128];  // conflict-free replicated-LUT gather
    v.y = p1[oo * 128];
    v.z = p2[oo * 128];
    v.w = p3[oo * 128];
    *(nfloat4*)(orow + (size_t)oo * NN) = v;
  }
}

// ---------------------------------------------------------------------------
extern "C" void kernel_launch(void* const* d_in, const int* in_sizes, int n_in,
                              void* d_out, int out_size, void* d_ws, size_t ws_size,
                              hipStream_t stream) {
  const float* x = (const float*)d_in[0];
  const int* ring = (const int*)d_in[1];
  const float* W = (const float*)d_in[2];
  const float* bias = (const float*)d_in[3];
  const float* gamma = (const float*)d_in[4];
  const float* beta = (const float*)d_in[5];
  const float* mean = (const float*)d_in[6];
  const float* var = (const float*)d_in[7];
  float* out = (float*)d_out;

  float* part = (float*)d_ws;  // 512 KB, fully overwritten -> no memset

  k_compute<<<dim3(NN / 1024, BB), 512, 0, stream>>>(x, W, ring, part);
  k_out<<<dim3(NN / 1024, DOUT / 32, BB), 256, 0, stream>>>(bias, gamma, beta, mean,
                                                            var, ring, part, out);
}